// Round 1
// baseline (135.319 us; speedup 1.0000x reference)
//
#include <hip/hip_runtime.h>
#include <math.h>

// Problem: B=16, H=W=256, C_hidden=150, K=20 value-iteration steps.
// Kernel 1: p = sigmoid( sum_c Wp[c] * relu(conv3x3(occ, Wh[c]) + bh[c]) )
//           (the 150-channel intermediate h is never materialized)
// Kernel 2: v0 = r; 20x: v = max(v, r + p*(maxpool3_SAME(v) - r));
//           out = occ > 0.49 ? v : -1
//           Halo-tiled: 64x64 extended tile, 24x24 output, 20-px halo,
//           v/r/p register-resident (4 waves x 16 rows, lanes = columns).

#define SENT -1e30f   // finite -inf stand-in; avoids 0*inf NaN in the update

__global__ __launch_bounds__(256) void conv_p_kernel(
    const float* __restrict__ image, const float* __restrict__ Wh,
    const float* __restrict__ bh, const float* __restrict__ Wp,
    float* __restrict__ pout)
{
    const int gx = blockIdx.x * 64 + (int)threadIdx.x;   // [0,256)
    const int gy = blockIdx.y * 4  + (int)threadIdx.y;   // [0,256)
    const int b  = blockIdx.z;
    const float* occ = image + (size_t)b * 131072;       // channel 0 plane

    // 3x3 neighborhood, zero-padded (conv SAME)
    float n[9];
#pragma unroll
    for (int ky = 0; ky < 3; ++ky) {
#pragma unroll
        for (int kx = 0; kx < 3; ++kx) {
            int yy = gy + ky - 1, xx = gx + kx - 1;
            bool ok = (yy >= 0) & (yy < 256) & (xx >= 0) & (xx < 256);
            n[ky * 3 + kx] = ok ? occ[yy * 256 + xx] : 0.f;
        }
    }

    // Channel loop: weight indices are wave-uniform -> scalar loads.
    float s = 0.f;
    for (int c = 0; c < 150; ++c) {
        const float* w = Wh + c * 9;
        float acc = bh[c];
#pragma unroll
        for (int k = 0; k < 9; ++k) acc = fmaf(w[k], n[k], acc);
        s = fmaf(Wp[c], fmaxf(acc, 0.f), s);
    }
    float pv = 1.f / (1.f + __expf(-s));
    pout[(size_t)b * 65536 + gy * 256 + gx] = pv;
}

__global__ __launch_bounds__(256) void mvprop_kernel(
    const float* __restrict__ image, const float* __restrict__ pbuf,
    float* __restrict__ out)
{
    const int tid  = threadIdx.x;
    const int w    = tid >> 6;        // wave id 0..3, owns rows 16w..16w+15
    const int lane = tid & 63;        // lane = extended-tile column
    const int b    = blockIdx.z;
    const int gx0  = blockIdx.x * 24 - 20;
    const int gy0  = blockIdx.y * 24 - 20;
    const int gx   = gx0 + lane;
    const bool xin = (gx >= 0) & (gx < 256);

    const float* rimg = image + (size_t)b * 131072 + 65536; // channel 1 plane
    const float* pp   = pbuf  + (size_t)b * 65536;

    float v[16], r[16], p[16];
#pragma unroll
    for (int i = 0; i < 16; ++i) {
        int gy = gy0 + w * 16 + i;
        bool inb = xin & (gy >= 0) & (gy < 256);
        r[i] = inb ? rimg[gy * 256 + gx] : SENT;
        p[i] = inb ? pp[gy * 256 + gx] : 0.f;
        v[i] = r[i];
    }

    __shared__ float eT[4][64], eB[4][64];  // wave-boundary row exchange

    for (int t = 0; t < 20; ++t) {
        eT[w][lane] = v[0];
        eB[w][lane] = v[15];
        __syncthreads();
        float above = (w > 0) ? eB[w - 1][lane] : SENT;
        float below = (w < 3) ? eT[w + 1][lane] : SENT;
        __syncthreads();

        float prev = above;
#pragma unroll
        for (int i = 0; i < 16; ++i) {
            float cur = v[i];
            float nxt = (i < 15) ? v[i + 1] : below;
            // vertical 3-max (register-only)
            float a = fmaxf(prev, fmaxf(cur, nxt));
            // horizontal 3-max via wave shuffles; clamped shuffle returns own
            // value, which is max-neutral == reference's -inf SAME padding
            float lft = __shfl_up(a, 1);
            float rgt = __shfl_down(a, 1);
            float m = fmaxf(a, fmaxf(lft, rgt));
            v[i] = fmaxf(cur, fmaf(p[i], m - r[i], r[i]));
            prev = cur;   // pre-update value for next row's vertical max
        }
    }

    // Store the valid 24x24 center, masked by occ
    int ox = lane - 20;
    if (ox >= 0 && ox < 24 && gx >= 0 && gx < 256) {
        const float* occ = image + (size_t)b * 131072;
#pragma unroll
        for (int i = 0; i < 16; ++i) {
            int row = w * 16 + i;
            int oy = row - 20;
            if (oy >= 0 && oy < 24) {
                int gy = gy0 + row;
                if (gy >= 0 && gy < 256) {
                    float ov = occ[gy * 256 + gx];
                    out[(size_t)b * 65536 + gy * 256 + gx] =
                        (ov > 0.49f) ? v[i] : -1.0f;
                }
            }
        }
    }
}

extern "C" void kernel_launch(void* const* d_in, const int* in_sizes, int n_in,
                              void* d_out, int out_size, void* d_ws, size_t ws_size,
                              hipStream_t stream) {
    const float* image = (const float*)d_in[0];  // (16,2,256,256)
    const float* Wh    = (const float*)d_in[1];  // (150,1,3,3)
    const float* bh    = (const float*)d_in[2];  // (150,)
    const float* Wp    = (const float*)d_in[3];  // (1,150,1,1)
    float* out  = (float*)d_out;                 // (16,1,256,256) f32
    float* pbuf = (float*)d_ws;                  // 4 MB scratch for p

    conv_p_kernel<<<dim3(4, 64, 16), dim3(64, 4), 0, stream>>>(image, Wh, bh, Wp, pbuf);
    // 11 = ceil(256/24) output tiles per axis
    mvprop_kernel<<<dim3(11, 11, 16), dim3(256), 0, stream>>>(image, pbuf, out);
}

// Round 2
// 80.574 us; speedup vs baseline: 1.6794x; 1.6794x over previous
//
#include <hip/hip_runtime.h>
#include <math.h>

// B=16, H=W=256, 150 hidden channels, K=20 value-iteration steps.
// Kernel 1 (conv_p): p = sigmoid(sum_c Wp[c]*relu(conv3x3(occ,Wh[c])+bh[c]))
//   1x4 pixel strip per thread: 4 independent FMA chains per channel (ILP),
//   wave-uniform weight indices -> scalar loads, float4 stores.
// Kernel 2 (mvprop): v0=r; 20x: v = max(v, r + p*(maxpool3_SAME(v)-r));
//   out = occ>0.49 ? v : -1.
//   Full-width tiles: lane owns 4 contiguous columns (wave covers all 256
//   cols -> NO x-halo). Block = 8 waves x 7 rows = 56 ext rows -> 16 output
//   rows; grid 16x16 = 256 blocks = 1 per CU. Ghost rows exchanged via
//   double-buffered LDS: 1 barrier/iter.

#define SENT -1e30f  // finite -inf stand-in; keeps fmaf(0, m-r, r) NaN-free

__global__ __launch_bounds__(256) void conv_p_kernel(
    const float* __restrict__ image, const float* __restrict__ Wh,
    const float* __restrict__ bh, const float* __restrict__ Wp,
    float* __restrict__ pout)
{
    const int gx = (int)threadIdx.x * 4;                  // strip start col
    const int gy = blockIdx.y * 4 + threadIdx.y;          // row
    const int b  = blockIdx.z;
    const float* occ = image + (size_t)b * 131072;        // channel 0 plane

    // 3x6 patch (rows gy-1..gy+1, cols gx-1..gx+4), zero-padded
    float n[3][6];
#pragma unroll
    for (int ky = 0; ky < 3; ++ky) {
        int yy = gy + ky - 1;
        bool yok = (yy >= 0) & (yy < 256);
#pragma unroll
        for (int kx = 0; kx < 6; ++kx) {
            int xx = gx + kx - 1;
            bool ok = yok & (xx >= 0) & (xx < 256);
            n[ky][kx] = ok ? occ[yy * 256 + xx] : 0.f;
        }
    }

    float s0 = 0.f, s1 = 0.f, s2 = 0.f, s3 = 0.f;
#pragma unroll 2
    for (int c = 0; c < 150; ++c) {
        const float* w = Wh + c * 9;                      // wave-uniform
        float bb = bh[c];
        float a0 = bb, a1 = bb, a2 = bb, a3 = bb;
#pragma unroll
        for (int ky = 0; ky < 3; ++ky) {
#pragma unroll
            for (int kx = 0; kx < 3; ++kx) {
                float wv = w[ky * 3 + kx];
                a0 = fmaf(wv, n[ky][kx],     a0);
                a1 = fmaf(wv, n[ky][kx + 1], a1);
                a2 = fmaf(wv, n[ky][kx + 2], a2);
                a3 = fmaf(wv, n[ky][kx + 3], a3);
            }
        }
        float wp = Wp[c];
        s0 = fmaf(wp, fmaxf(a0, 0.f), s0);
        s1 = fmaf(wp, fmaxf(a1, 0.f), s1);
        s2 = fmaf(wp, fmaxf(a2, 0.f), s2);
        s3 = fmaf(wp, fmaxf(a3, 0.f), s3);
    }

    float4 o;
    o.x = 1.f / (1.f + __expf(-s0));
    o.y = 1.f / (1.f + __expf(-s1));
    o.z = 1.f / (1.f + __expf(-s2));
    o.w = 1.f / (1.f + __expf(-s3));
    *(float4*)&pout[(size_t)b * 65536 + gy * 256 + gx] = o;
}

__global__ __launch_bounds__(512, 2) void mvprop_kernel(
    const float* __restrict__ image, const float* __restrict__ pbuf,
    float* __restrict__ out)
{
    const int tid  = threadIdx.x;
    const int w    = tid >> 6;          // wave 0..7, owns ext rows 7w..7w+6
    const int lane = tid & 63;          // lane owns cols 4*lane..4*lane+3
    const int b    = blockIdx.z;
    const int gy0  = blockIdx.y * 16 - 20;   // ext row 0 -> global row gy0
    const int x4   = lane * 4;

    const float* rimg = image + (size_t)b * 131072 + 65536;  // channel 1
    const float* pp   = pbuf  + (size_t)b * 65536;

    float v[7][4], r[7][4], p[7][4];
#pragma unroll
    for (int i = 0; i < 7; ++i) {
        int gy = gy0 + w * 7 + i;
        if (gy >= 0 && gy < 256) {
            float4 rv = *(const float4*)&rimg[gy * 256 + x4];
            float4 pv = *(const float4*)&pp[gy * 256 + x4];
            r[i][0] = rv.x; r[i][1] = rv.y; r[i][2] = rv.z; r[i][3] = rv.w;
            p[i][0] = pv.x; p[i][1] = pv.y; p[i][2] = pv.z; p[i][3] = pv.w;
        } else {
            r[i][0] = r[i][1] = r[i][2] = r[i][3] = SENT;
            p[i][0] = p[i][1] = p[i][2] = p[i][3] = 0.f;
        }
        v[i][0] = r[i][0]; v[i][1] = r[i][1];
        v[i][2] = r[i][2]; v[i][3] = r[i][3];
    }

    // double-buffered ghost rows: first (gT) and last (gB) row of each wave
    __shared__ float4 gT[2][8][64];
    __shared__ float4 gB[2][8][64];

    for (int t = 0; t < 20; ++t) {
        int bf = t & 1;
        gT[bf][w][lane] = make_float4(v[0][0], v[0][1], v[0][2], v[0][3]);
        gB[bf][w][lane] = make_float4(v[6][0], v[6][1], v[6][2], v[6][3]);
        __syncthreads();
        float4 abv = (w > 0) ? gB[bf][w - 1][lane]
                             : make_float4(SENT, SENT, SENT, SENT);
        float4 blw = (w < 7) ? gT[bf][w + 1][lane]
                             : make_float4(SENT, SENT, SENT, SENT);

        float pv0 = abv.x, pv1 = abv.y, pv2 = abv.z, pv3 = abv.w;
#pragma unroll
        for (int i = 0; i < 7; ++i) {
            float c0 = v[i][0], c1 = v[i][1], c2 = v[i][2], c3 = v[i][3];
            float n0, n1, n2, n3;
            if (i < 6) { n0 = v[i+1][0]; n1 = v[i+1][1]; n2 = v[i+1][2]; n3 = v[i+1][3]; }
            else       { n0 = blw.x;     n1 = blw.y;     n2 = blw.z;     n3 = blw.w;     }
            // vertical 3-max (all in registers)
            float vm0 = fmaxf(pv0, fmaxf(c0, n0));
            float vm1 = fmaxf(pv1, fmaxf(c1, n1));
            float vm2 = fmaxf(pv2, fmaxf(c2, n2));
            float vm3 = fmaxf(pv3, fmaxf(c3, n3));
            // horizontal: only the 2 boundary cols need cross-lane values
            float lL = __shfl_up(vm3, 1);
            lL = (lane == 0) ? SENT : lL;     // col -1 outside image
            float rR = __shfl_down(vm0, 1);
            rR = (lane == 63) ? SENT : rR;    // col 256 outside image
            float h0 = fmaxf(lL,  fmaxf(vm0, vm1));
            float h1 = fmaxf(vm0, fmaxf(vm1, vm2));
            float h2 = fmaxf(vm1, fmaxf(vm2, vm3));
            float h3 = fmaxf(vm2, fmaxf(vm3, rR));
            v[i][0] = fmaxf(c0, fmaf(p[i][0], h0 - r[i][0], r[i][0]));
            v[i][1] = fmaxf(c1, fmaf(p[i][1], h1 - r[i][1], r[i][1]));
            v[i][2] = fmaxf(c2, fmaf(p[i][2], h2 - r[i][2], r[i][2]));
            v[i][3] = fmaxf(c3, fmaf(p[i][3], h3 - r[i][3], r[i][3]));
            pv0 = c0; pv1 = c1; pv2 = c2; pv3 = c3;  // old value for next row
        }
    }

    // store valid output rows (ext rows 20..35), masked by occ
    const float* occ = image + (size_t)b * 131072;
#pragma unroll
    for (int i = 0; i < 7; ++i) {
        int e = w * 7 + i;
        if (e >= 20 && e < 36) {
            int gy = gy0 + e;   // in [by*16, by*16+16) subset of [0,256)
            float4 ov = *(const float4*)&occ[gy * 256 + x4];
            float4 o;
            o.x = (ov.x > 0.49f) ? v[i][0] : -1.f;
            o.y = (ov.y > 0.49f) ? v[i][1] : -1.f;
            o.z = (ov.z > 0.49f) ? v[i][2] : -1.f;
            o.w = (ov.w > 0.49f) ? v[i][3] : -1.f;
            *(float4*)&out[(size_t)b * 65536 + gy * 256 + x4] = o;
        }
    }
}

extern "C" void kernel_launch(void* const* d_in, const int* in_sizes, int n_in,
                              void* d_out, int out_size, void* d_ws, size_t ws_size,
                              hipStream_t stream) {
    const float* image = (const float*)d_in[0];  // (16,2,256,256)
    const float* Wh    = (const float*)d_in[1];  // (150,1,3,3)
    const float* bh    = (const float*)d_in[2];  // (150,)
    const float* Wp    = (const float*)d_in[3];  // (1,150,1,1)
    float* out  = (float*)d_out;                 // (16,1,256,256) f32
    float* pbuf = (float*)d_ws;                  // 4 MB scratch for p

    conv_p_kernel<<<dim3(1, 64, 16), dim3(64, 4), 0, stream>>>(image, Wh, bh, Wp, pbuf);
    mvprop_kernel<<<dim3(1, 16, 16), dim3(512), 0, stream>>>(image, pbuf, out);
}

// Round 3
// 60.255 us; speedup vs baseline: 2.2458x; 1.3372x over previous
//
#include <hip/hip_runtime.h>
#include <hip/hip_bf16.h>
#include <math.h>

// B=16, H=W=256, 150 hidden channels, K=20 value-iteration steps.
//
// Kernel 1 (conv_p_mfma): p = sigmoid(sum_c Wp[c]*relu(conv3x3(occ,Wh[c])+bh[c]))
//   Implicit GEMM on matrix cores: C[ch,px] = A[ch,k]*B[k,px],
//   mfma_f32_32x32x16_bf16, K=16 = 9 taps + bias slot (B[9,:]=1, A[:,9]=bh).
//   5 channel-groups of 32 (150->160 padded). A-frags built once per wave.
//   Per 32-px strip: 3 row loads + 9 shfl + pack -> B frag -> 5 MFMA ->
//   relu*Wp reduction (Wp via LDS float4 broadcast) -> shfl_xor(32) -> sigmoid.
//
// Kernel 2 (mvprop): unchanged from R2 (passed, ~22us).

#define SENT -1e30f

typedef short short8 __attribute__((ext_vector_type(8)));
typedef float f32x16 __attribute__((ext_vector_type(16)));

__device__ inline ushort f2bf(float f) {
    __hip_bfloat16 h = __float2bfloat16(f);
    ushort u; __builtin_memcpy(&u, &h, 2);
    return u;
}

__device__ inline short8 pack8(const float* src) {
    short8 r;
#pragma unroll
    for (int j = 0; j < 8; ++j) r[j] = (short)f2bf(src[j]);
    return r;
}

__global__ __launch_bounds__(256) void conv_p_mfma(
    const float* __restrict__ image, const float* __restrict__ Wh,
    const float* __restrict__ bh, const float* __restrict__ Wp,
    float* __restrict__ pout)
{
    const int tid  = threadIdx.x;
    const int wv   = tid >> 6;
    const int lane = tid & 63;
    const int half = lane >> 5;      // k-block selector for MFMA operands
    const int col0 = lane & 31;
    const int b    = blockIdx.z;
    const int y    = blockIdx.x * 4 + wv;          // each wave owns one row
    const float* occ = image + (size_t)b * 131072; // channel 0 plane

    // Wp broadcast table in LDS (padded 160)
    __shared__ __align__(16) float lds_wp[160];
    if (tid < 160) lds_wp[tid] = (tid < 150) ? Wp[tid] : 0.f;
    __syncthreads();

    // ---- A fragments (weights), built once: group g covers ch = 32g..32g+31
    // A[ch,k]: lane holds row ch=32g+col0, k = 8*half + j.
    // k=0..8 -> Wh taps, k=9 -> bias, k>=10 -> 0.
    short8 afr[5];
#pragma unroll
    for (int g = 0; g < 5; ++g) {
        int ch = 32 * g + col0;
        bool ok = ch < 150;
        float w10[10];
#pragma unroll
        for (int k = 0; k < 9; ++k) w10[k] = ok ? Wh[ch * 9 + k] : 0.f;
        w10[9] = ok ? bh[ch] : 0.f;
        float src[8];
#pragma unroll
        for (int j = 0; j < 8; ++j)
            src[j] = half ? ((j == 0) ? w10[8] : (j == 1) ? w10[9] : 0.f)
                          : w10[j];
        afr[g] = pack8(src);
    }

    const f32x16 kZero = {};

    // row loader: lanes 0..33 hold cols x0-1 .. x0+32 of rows y-1..y+1
    auto loadRows = [&](int x0, float r[3]) {
        int cc = x0 - 1 + lane;
        bool cok = (lane < 34) & (cc >= 0) & (cc < 256);
#pragma unroll
        for (int dy = 0; dy < 3; ++dy) {
            int yy = y + dy - 1;
            bool ok = cok & (yy >= 0) & (yy < 256);
            r[dy] = ok ? occ[yy * 256 + cc] : 0.f;
        }
    };

    float cur[3], nxt[3];
    loadRows(0, cur);

    for (int x0 = 0; x0 < 256; x0 += 32) {
        // prefetch next strip (hides HBM/L2 latency under compute)
        if (x0 + 32 < 256) loadRows(x0 + 32, nxt);
        else { nxt[0] = 0.f; nxt[1] = 0.f; nxt[2] = 0.f; }

        // taps: pixel px = x0+col0 needs cols px-1..px+1 = loaded lanes col0..col0+2
        float t[9];
#pragma unroll
        for (int dy = 0; dy < 3; ++dy) {
            t[dy * 3 + 0] = __shfl(cur[dy], col0);
            t[dy * 3 + 1] = __shfl(cur[dy], col0 + 1);
            t[dy * 3 + 2] = __shfl(cur[dy], col0 + 2);
        }

        // B fragment: col px=col0, k = 8*half + j. lower: k=0..7 taps;
        // upper: k=8 tap, k=9 bias-one, k>=10 zero.
        float src[8];
#pragma unroll
        for (int j = 0; j < 8; ++j)
            src[j] = half ? ((j == 0) ? t[8] : (j == 1) ? 1.0f : 0.f)
                          : t[j];
        short8 bfr = pack8(src);

        f32x16 d[5];
#pragma unroll
        for (int g = 0; g < 5; ++g)
            d[g] = __builtin_amdgcn_mfma_f32_32x32x16_bf16(afr[g], bfr, kZero, 0, 0, 0);

        // reduction: s = sum_ch Wp[ch]*relu(h[ch]); acc row = (reg&3)+8*(reg>>2)+4*half
        float s0 = 0.f, s1 = 0.f, s2 = 0.f, s3 = 0.f;
#pragma unroll
        for (int g = 0; g < 5; ++g) {
#pragma unroll
            for (int q = 0; q < 4; ++q) {
                const float4 wp4 = *(const float4*)&lds_wp[32 * g + 8 * q + 4 * half];
                s0 = fmaf(wp4.x, fmaxf(d[g][q * 4 + 0], 0.f), s0);
                s1 = fmaf(wp4.y, fmaxf(d[g][q * 4 + 1], 0.f), s1);
                s2 = fmaf(wp4.z, fmaxf(d[g][q * 4 + 2], 0.f), s2);
                s3 = fmaf(wp4.w, fmaxf(d[g][q * 4 + 3], 0.f), s3);
            }
        }
        float s = (s0 + s1) + (s2 + s3);
        s += __shfl_xor(s, 32);     // combine the two half-wave channel sets

        float p = 1.f / (1.f + __expf(-s));
        if (lane < 32)
            pout[(size_t)b * 65536 + y * 256 + x0 + lane] = p;

        cur[0] = nxt[0]; cur[1] = nxt[1]; cur[2] = nxt[2];
    }
}

__global__ __launch_bounds__(512, 2) void mvprop_kernel(
    const float* __restrict__ image, const float* __restrict__ pbuf,
    float* __restrict__ out)
{
    const int tid  = threadIdx.x;
    const int w    = tid >> 6;          // wave 0..7, owns ext rows 7w..7w+6
    const int lane = tid & 63;          // lane owns cols 4*lane..4*lane+3
    const int b    = blockIdx.z;
    const int gy0  = blockIdx.y * 16 - 20;   // ext row 0 -> global row gy0
    const int x4   = lane * 4;

    const float* rimg = image + (size_t)b * 131072 + 65536;  // channel 1
    const float* pp   = pbuf  + (size_t)b * 65536;

    float v[7][4], r[7][4], p[7][4];
#pragma unroll
    for (int i = 0; i < 7; ++i) {
        int gy = gy0 + w * 7 + i;
        if (gy >= 0 && gy < 256) {
            float4 rv = *(const float4*)&rimg[gy * 256 + x4];
            float4 pv = *(const float4*)&pp[gy * 256 + x4];
            r[i][0] = rv.x; r[i][1] = rv.y; r[i][2] = rv.z; r[i][3] = rv.w;
            p[i][0] = pv.x; p[i][1] = pv.y; p[i][2] = pv.z; p[i][3] = pv.w;
        } else {
            r[i][0] = r[i][1] = r[i][2] = r[i][3] = SENT;
            p[i][0] = p[i][1] = p[i][2] = p[i][3] = 0.f;
        }
        v[i][0] = r[i][0]; v[i][1] = r[i][1];
        v[i][2] = r[i][2]; v[i][3] = r[i][3];
    }

    __shared__ float4 gT[2][8][64];
    __shared__ float4 gB[2][8][64];

    for (int t = 0; t < 20; ++t) {
        int bf = t & 1;
        gT[bf][w][lane] = make_float4(v[0][0], v[0][1], v[0][2], v[0][3]);
        gB[bf][w][lane] = make_float4(v[6][0], v[6][1], v[6][2], v[6][3]);
        __syncthreads();
        float4 abv = (w > 0) ? gB[bf][w - 1][lane]
                             : make_float4(SENT, SENT, SENT, SENT);
        float4 blw = (w < 7) ? gT[bf][w + 1][lane]
                             : make_float4(SENT, SENT, SENT, SENT);

        float pv0 = abv.x, pv1 = abv.y, pv2 = abv.z, pv3 = abv.w;
#pragma unroll
        for (int i = 0; i < 7; ++i) {
            float c0 = v[i][0], c1 = v[i][1], c2 = v[i][2], c3 = v[i][3];
            float n0, n1, n2, n3;
            if (i < 6) { n0 = v[i+1][0]; n1 = v[i+1][1]; n2 = v[i+1][2]; n3 = v[i+1][3]; }
            else       { n0 = blw.x;     n1 = blw.y;     n2 = blw.z;     n3 = blw.w;     }
            float vm0 = fmaxf(pv0, fmaxf(c0, n0));
            float vm1 = fmaxf(pv1, fmaxf(c1, n1));
            float vm2 = fmaxf(pv2, fmaxf(c2, n2));
            float vm3 = fmaxf(pv3, fmaxf(c3, n3));
            float lL = __shfl_up(vm3, 1);
            lL = (lane == 0) ? SENT : lL;
            float rR = __shfl_down(vm0, 1);
            rR = (lane == 63) ? SENT : rR;
            float h0 = fmaxf(lL,  fmaxf(vm0, vm1));
            float h1 = fmaxf(vm0, fmaxf(vm1, vm2));
            float h2 = fmaxf(vm1, fmaxf(vm2, vm3));
            float h3 = fmaxf(vm2, fmaxf(vm3, rR));
            v[i][0] = fmaxf(c0, fmaf(p[i][0], h0 - r[i][0], r[i][0]));
            v[i][1] = fmaxf(c1, fmaf(p[i][1], h1 - r[i][1], r[i][1]));
            v[i][2] = fmaxf(c2, fmaf(p[i][2], h2 - r[i][2], r[i][2]));
            v[i][3] = fmaxf(c3, fmaf(p[i][3], h3 - r[i][3], r[i][3]));
            pv0 = c0; pv1 = c1; pv2 = c2; pv3 = c3;
        }
    }

    const float* occ = image + (size_t)b * 131072;
#pragma unroll
    for (int i = 0; i < 7; ++i) {
        int e = w * 7 + i;
        if (e >= 20 && e < 36) {
            int gy = gy0 + e;
            float4 ov = *(const float4*)&occ[gy * 256 + x4];
            float4 o;
            o.x = (ov.x > 0.49f) ? v[i][0] : -1.f;
            o.y = (ov.y > 0.49f) ? v[i][1] : -1.f;
            o.z = (ov.z > 0.49f) ? v[i][2] : -1.f;
            o.w = (ov.w > 0.49f) ? v[i][3] : -1.f;
            *(float4*)&out[(size_t)b * 65536 + gy * 256 + x4] = o;
        }
    }
}

extern "C" void kernel_launch(void* const* d_in, const int* in_sizes, int n_in,
                              void* d_out, int out_size, void* d_ws, size_t ws_size,
                              hipStream_t stream) {
    const float* image = (const float*)d_in[0];  // (16,2,256,256)
    const float* Wh    = (const float*)d_in[1];  // (150,1,3,3)
    const float* bh    = (const float*)d_in[2];  // (150,)
    const float* Wp    = (const float*)d_in[3];  // (1,150,1,1)
    float* out  = (float*)d_out;                 // (16,1,256,256) f32
    float* pbuf = (float*)d_ws;                  // 4 MB scratch for p

    conv_p_mfma<<<dim3(64, 1, 16), dim3(256), 0, stream>>>(image, Wh, bh, Wp, pbuf);
    mvprop_kernel<<<dim3(1, 16, 16), dim3(512), 0, stream>>>(image, pbuf, out);
}

// Round 4
// 60.146 us; speedup vs baseline: 2.2499x; 1.0018x over previous
//
#include <hip/hip_runtime.h>
#include <hip/hip_bf16.h>
#include <math.h>

// B=16, H=W=256, 150 hidden channels, K=20 value-iteration steps.
//
// Kernel 1 (conv_p_mfma): p = sigmoid(sum_c Wp[c]*relu(conv3x3(occ,Wh[c])+bh[c]))
//   Implicit GEMM on matrix cores, mfma_f32_32x32x16_bf16, K=16 = 9 taps +
//   bias slot. 5 channel-groups of 32 (150->160 padded).
//   FULLY FLATTENED (R3): no pointer-passed helpers, no lambdas, no arrays —
//   named fragments only, so nothing can land in scratch (rule #20).
//
// Kernel 2 (mvprop): unchanged from R2 (~22.9us by subtraction).

#define SENT -1e30f

typedef short short8 __attribute__((ext_vector_type(8)));
typedef float f32x16 __attribute__((ext_vector_type(16)));

__device__ __forceinline__ short bfb(float f) {
    __hip_bfloat16 h = __float2bfloat16(f);
    ushort u; __builtin_memcpy(&u, &h, 2);
    return (short)u;
}

__global__ __launch_bounds__(256) void conv_p_mfma(
    const float* __restrict__ image, const float* __restrict__ Wh,
    const float* __restrict__ bh, const float* __restrict__ Wp,
    float* __restrict__ pout)
{
    const int tid  = threadIdx.x;
    const int wv   = tid >> 6;
    const int lane = tid & 63;
    const int half = lane >> 5;      // k-block selector (k = 8*half + j)
    const int col0 = lane & 31;
    const int b    = blockIdx.z;
    const int y    = blockIdx.x * 4 + wv;          // each wave owns one row
    const float* occ = image + (size_t)b * 131072; // channel 0 plane

    __shared__ __align__(16) float lds_wp[160];
    if (tid < 160) lds_wp[tid] = (tid < 150) ? Wp[tid] : 0.f;
    __syncthreads();

    // ---- A fragments (built once). A[ch,k]: lane row ch=32g+col0,
    // k=0..8 -> Wh taps, k=9 -> bias, k>=10 -> 0.
    short8 afr0, afr1, afr2, afr3, afr4;
#define BUILD_A(AFR, G)                                                      \
    {                                                                        \
        int ch = 32 * (G) + col0;                                            \
        bool ok = ch < 150;                                                  \
        int cs = ok ? ch : 0;                                                \
        float w0 = ok ? Wh[cs*9+0] : 0.f, w1 = ok ? Wh[cs*9+1] : 0.f;        \
        float w2 = ok ? Wh[cs*9+2] : 0.f, w3 = ok ? Wh[cs*9+3] : 0.f;        \
        float w4 = ok ? Wh[cs*9+4] : 0.f, w5 = ok ? Wh[cs*9+5] : 0.f;        \
        float w6 = ok ? Wh[cs*9+6] : 0.f, w7 = ok ? Wh[cs*9+7] : 0.f;        \
        float w8 = ok ? Wh[cs*9+8] : 0.f, bb = ok ? bh[cs]     : 0.f;        \
        AFR[0] = half ? bfb(w8) : bfb(w0);                                   \
        AFR[1] = half ? bfb(bb) : bfb(w1);                                   \
        AFR[2] = half ? (short)0 : bfb(w2);                                  \
        AFR[3] = half ? (short)0 : bfb(w3);                                  \
        AFR[4] = half ? (short)0 : bfb(w4);                                  \
        AFR[5] = half ? (short)0 : bfb(w5);                                  \
        AFR[6] = half ? (short)0 : bfb(w6);                                  \
        AFR[7] = half ? (short)0 : bfb(w7);                                  \
    }
    BUILD_A(afr0, 0) BUILD_A(afr1, 1) BUILD_A(afr2, 2)
    BUILD_A(afr3, 3) BUILD_A(afr4, 4)
#undef BUILD_A

    const f32x16 kZero = {};
    const short  kOne  = (short)0x3F80;   // bf16(1.0) for the bias slot

    // row registers: lanes 0..33 hold cols x0-1..x0+32 of rows y-1,y,y+1
    float cur0, cur1, cur2, nxt0, nxt1, nxt2;
    {
        int cc = lane - 1;
        bool cok = (lane < 34) & (cc >= 0);
        cur0 = (cok & (y >= 1))   ? occ[(y - 1) * 256 + cc] : 0.f;
        cur1 = cok                ? occ[y * 256 + cc]       : 0.f;
        cur2 = (cok & (y <= 254)) ? occ[(y + 1) * 256 + cc] : 0.f;
    }

    for (int x0 = 0; x0 < 256; x0 += 32) {
        // prefetch next strip
        if (x0 < 224) {
            int cc = x0 + 31 + lane;
            bool cok = (lane < 34) & (cc < 256);
            nxt0 = (cok & (y >= 1))   ? occ[(y - 1) * 256 + cc] : 0.f;
            nxt1 = cok                ? occ[y * 256 + cc]       : 0.f;
            nxt2 = (cok & (y <= 254)) ? occ[(y + 1) * 256 + cc] : 0.f;
        } else { nxt0 = 0.f; nxt1 = 0.f; nxt2 = 0.f; }

        // 3x3 taps for pixel px = x0+col0 (loaded lanes col0..col0+2)
        float t0 = __shfl(cur0, col0), t1 = __shfl(cur0, col0 + 1), t2 = __shfl(cur0, col0 + 2);
        float t3 = __shfl(cur1, col0), t4 = __shfl(cur1, col0 + 1), t5 = __shfl(cur1, col0 + 2);
        float t6 = __shfl(cur2, col0), t7 = __shfl(cur2, col0 + 1), t8 = __shfl(cur2, col0 + 2);

        // B fragment: col=col0, lower half k=0..7 -> t0..t7; upper k=8 -> t8,
        // k=9 -> 1.0 (bias), k>=10 -> 0
        short8 bfr;
        bfr[0] = half ? bfb(t8) : bfb(t0);
        bfr[1] = half ? kOne    : bfb(t1);
        bfr[2] = half ? (short)0 : bfb(t2);
        bfr[3] = half ? (short)0 : bfb(t3);
        bfr[4] = half ? (short)0 : bfb(t4);
        bfr[5] = half ? (short)0 : bfb(t5);
        bfr[6] = half ? (short)0 : bfb(t6);
        bfr[7] = half ? (short)0 : bfb(t7);

        f32x16 d0 = __builtin_amdgcn_mfma_f32_32x32x16_bf16(afr0, bfr, kZero, 0, 0, 0);
        f32x16 d1 = __builtin_amdgcn_mfma_f32_32x32x16_bf16(afr1, bfr, kZero, 0, 0, 0);
        f32x16 d2 = __builtin_amdgcn_mfma_f32_32x32x16_bf16(afr2, bfr, kZero, 0, 0, 0);
        f32x16 d3 = __builtin_amdgcn_mfma_f32_32x32x16_bf16(afr3, bfr, kZero, 0, 0, 0);
        f32x16 d4 = __builtin_amdgcn_mfma_f32_32x32x16_bf16(afr4, bfr, kZero, 0, 0, 0);

        // s = sum_ch Wp[ch]*relu(h[ch]); C-row = (reg&3) + 8*(reg>>2) + 4*half
        float s0 = 0.f, s1 = 0.f, s2 = 0.f, s3 = 0.f;
#define RED(D, G)                                                            \
    {                                                                        \
        const float4 wA = *(const float4*)&lds_wp[32 * (G) + 0  + 4 * half]; \
        const float4 wB = *(const float4*)&lds_wp[32 * (G) + 8  + 4 * half]; \
        const float4 wC = *(const float4*)&lds_wp[32 * (G) + 16 + 4 * half]; \
        const float4 wD = *(const float4*)&lds_wp[32 * (G) + 24 + 4 * half]; \
        s0 = fmaf(wA.x, fmaxf(D[0],  0.f), s0);                              \
        s1 = fmaf(wA.y, fmaxf(D[1],  0.f), s1);                              \
        s2 = fmaf(wA.z, fmaxf(D[2],  0.f), s2);                              \
        s3 = fmaf(wA.w, fmaxf(D[3],  0.f), s3);                              \
        s0 = fmaf(wB.x, fmaxf(D[4],  0.f), s0);                              \
        s1 = fmaf(wB.y, fmaxf(D[5],  0.f), s1);                              \
        s2 = fmaf(wB.z, fmaxf(D[6],  0.f), s2);                              \
        s3 = fmaf(wB.w, fmaxf(D[7],  0.f), s3);                              \
        s0 = fmaf(wC.x, fmaxf(D[8],  0.f), s0);                              \
        s1 = fmaf(wC.y, fmaxf(D[9],  0.f), s1);                              \
        s2 = fmaf(wC.z, fmaxf(D[10], 0.f), s2);                              \
        s3 = fmaf(wC.w, fmaxf(D[11], 0.f), s3);                              \
        s0 = fmaf(wD.x, fmaxf(D[12], 0.f), s0);                              \
        s1 = fmaf(wD.y, fmaxf(D[13], 0.f), s1);                              \
        s2 = fmaf(wD.z, fmaxf(D[14], 0.f), s2);                              \
        s3 = fmaf(wD.w, fmaxf(D[15], 0.f), s3);                              \
    }
        RED(d0, 0) RED(d1, 1) RED(d2, 2) RED(d3, 3) RED(d4, 4)
#undef RED

        float s = (s0 + s1) + (s2 + s3);
        s += __shfl_xor(s, 32);   // combine the two half-wave channel sets

        float p = 1.f / (1.f + __expf(-s));
        if (lane < 32)
            pout[(size_t)b * 65536 + y * 256 + x0 + lane] = p;

        cur0 = nxt0; cur1 = nxt1; cur2 = nxt2;
    }
}

__global__ __launch_bounds__(512, 2) void mvprop_kernel(
    const float* __restrict__ image, const float* __restrict__ pbuf,
    float* __restrict__ out)
{
    const int tid  = threadIdx.x;
    const int w    = tid >> 6;          // wave 0..7, owns ext rows 7w..7w+6
    const int lane = tid & 63;          // lane owns cols 4*lane..4*lane+3
    const int b    = blockIdx.z;
    const int gy0  = blockIdx.y * 16 - 20;   // ext row 0 -> global row gy0
    const int x4   = lane * 4;

    const float* rimg = image + (size_t)b * 131072 + 65536;  // channel 1
    const float* pp   = pbuf  + (size_t)b * 65536;

    float v[7][4], r[7][4], p[7][4];
#pragma unroll
    for (int i = 0; i < 7; ++i) {
        int gy = gy0 + w * 7 + i;
        if (gy >= 0 && gy < 256) {
            float4 rv = *(const float4*)&rimg[gy * 256 + x4];
            float4 pv = *(const float4*)&pp[gy * 256 + x4];
            r[i][0] = rv.x; r[i][1] = rv.y; r[i][2] = rv.z; r[i][3] = rv.w;
            p[i][0] = pv.x; p[i][1] = pv.y; p[i][2] = pv.z; p[i][3] = pv.w;
        } else {
            r[i][0] = r[i][1] = r[i][2] = r[i][3] = SENT;
            p[i][0] = p[i][1] = p[i][2] = p[i][3] = 0.f;
        }
        v[i][0] = r[i][0]; v[i][1] = r[i][1];
        v[i][2] = r[i][2]; v[i][3] = r[i][3];
    }

    __shared__ float4 gT[2][8][64];
    __shared__ float4 gB[2][8][64];

    for (int t = 0; t < 20; ++t) {
        int bf = t & 1;
        gT[bf][w][lane] = make_float4(v[0][0], v[0][1], v[0][2], v[0][3]);
        gB[bf][w][lane] = make_float4(v[6][0], v[6][1], v[6][2], v[6][3]);
        __syncthreads();
        float4 abv = (w > 0) ? gB[bf][w - 1][lane]
                             : make_float4(SENT, SENT, SENT, SENT);
        float4 blw = (w < 7) ? gT[bf][w + 1][lane]
                             : make_float4(SENT, SENT, SENT, SENT);

        float pv0 = abv.x, pv1 = abv.y, pv2 = abv.z, pv3 = abv.w;
#pragma unroll
        for (int i = 0; i < 7; ++i) {
            float c0 = v[i][0], c1 = v[i][1], c2 = v[i][2], c3 = v[i][3];
            float n0, n1, n2, n3;
            if (i < 6) { n0 = v[i+1][0]; n1 = v[i+1][1]; n2 = v[i+1][2]; n3 = v[i+1][3]; }
            else       { n0 = blw.x;     n1 = blw.y;     n2 = blw.z;     n3 = blw.w;     }
            float vm0 = fmaxf(pv0, fmaxf(c0, n0));
            float vm1 = fmaxf(pv1, fmaxf(c1, n1));
            float vm2 = fmaxf(pv2, fmaxf(c2, n2));
            float vm3 = fmaxf(pv3, fmaxf(c3, n3));
            float lL = __shfl_up(vm3, 1);
            lL = (lane == 0) ? SENT : lL;
            float rR = __shfl_down(vm0, 1);
            rR = (lane == 63) ? SENT : rR;
            float h0 = fmaxf(lL,  fmaxf(vm0, vm1));
            float h1 = fmaxf(vm0, fmaxf(vm1, vm2));
            float h2 = fmaxf(vm1, fmaxf(vm2, vm3));
            float h3 = fmaxf(vm2, fmaxf(vm3, rR));
            v[i][0] = fmaxf(c0, fmaf(p[i][0], h0 - r[i][0], r[i][0]));
            v[i][1] = fmaxf(c1, fmaf(p[i][1], h1 - r[i][1], r[i][1]));
            v[i][2] = fmaxf(c2, fmaf(p[i][2], h2 - r[i][2], r[i][2]));
            v[i][3] = fmaxf(c3, fmaf(p[i][3], h3 - r[i][3], r[i][3]));
            pv0 = c0; pv1 = c1; pv2 = c2; pv3 = c3;
        }
    }

    const float* occ = image + (size_t)b * 131072;
#pragma unroll
    for (int i = 0; i < 7; ++i) {
        int e = w * 7 + i;
        if (e >= 20 && e < 36) {
            int gy = gy0 + e;
            float4 ov = *(const float4*)&occ[gy * 256 + x4];
            float4 o;
            o.x = (ov.x > 0.49f) ? v[i][0] : -1.f;
            o.y = (ov.y > 0.49f) ? v[i][1] : -1.f;
            o.z = (ov.z > 0.49f) ? v[i][2] : -1.f;
            o.w = (ov.w > 0.49f) ? v[i][3] : -1.f;
            *(float4*)&out[(size_t)b * 65536 + gy * 256 + x4] = o;
        }
    }
}

extern "C" void kernel_launch(void* const* d_in, const int* in_sizes, int n_in,
                              void* d_out, int out_size, void* d_ws, size_t ws_size,
                              hipStream_t stream) {
    const float* image = (const float*)d_in[0];  // (16,2,256,256)
    const float* Wh    = (const float*)d_in[1];  // (150,1,3,3)
    const float* bh    = (const float*)d_in[2];  // (150,)
    const float* Wp    = (const float*)d_in[3];  // (1,150,1,1)
    float* out  = (float*)d_out;                 // (16,1,256,256) f32
    float* pbuf = (float*)d_ws;                  // 4 MB scratch for p

    conv_p_mfma<<<dim3(64, 1, 16), dim3(256), 0, stream>>>(image, Wh, bh, Wp, pbuf);
    mvprop_kernel<<<dim3(1, 16, 16), dim3(512), 0, stream>>>(image, pbuf, out);
}

// Round 5
// 53.434 us; speedup vs baseline: 2.5325x; 1.1256x over previous
//
#include <hip/hip_runtime.h>
#include <hip/hip_bf16.h>
#include <math.h>

// B=16, H=W=256, 150 hidden channels, K=20 value-iteration steps.
//
// pack_a_kernel: packs conv weights+bias into MFMA A-fragment layout in d_ws.
// conv_p_mfma:   p = sigmoid(sum_c Wp[c]*relu(conv3x3(occ,Wh[c])+bh[c]))
//   mfma_f32_32x32x16_bf16, K=16 = 9 taps + bias slot, 5 channel-groups.
//   R5: strip-per-wave (32k waves), pre-packed A, cvt_pk B-frag,
//   launch_bounds(256,4) to stay under the 128-VGPR occupancy cliff.
// mvprop_kernel: unchanged from R2 (~20.6us by subtraction).

#define SENT -1e30f

typedef short short8 __attribute__((ext_vector_type(8)));
typedef float f32x16 __attribute__((ext_vector_type(16)));

__device__ __forceinline__ uint32_t pkbf(float lo, float hi) {
    uint32_t r;
    asm("v_cvt_pk_bf16_f32 %0, %1, %2" : "=v"(r) : "v"(lo), "v"(hi));
    return r;
}

__device__ __forceinline__ uint32_t bfu(float f) {
    __hip_bfloat16 h = __float2bfloat16(f);
    ushort u; __builtin_memcpy(&u, &h, 2);
    return (uint32_t)u;
}

// ---- setup: pack A[ch,k] fragments once. uint4 wsA[g][lane].
// lane=(half,col0): ch=32g+col0; half=0 -> k=0..7 = taps w0..w7;
// half=1 -> k=8 = w8, k=9 = bias, k>=10 = 0.
__global__ void pack_a_kernel(const float* __restrict__ Wh,
                              const float* __restrict__ bh,
                              uint4* __restrict__ wsA)
{
    const int lane = threadIdx.x;     // 0..63
    const int half = lane >> 5;
    const int col0 = lane & 31;
#pragma unroll
    for (int g = 0; g < 5; ++g) {
        int ch = 32 * g + col0;
        bool ok = ch < 150;
        int cs = ok ? ch : 0;
        float w0 = ok ? Wh[cs*9+0] : 0.f, w1 = ok ? Wh[cs*9+1] : 0.f;
        float w2 = ok ? Wh[cs*9+2] : 0.f, w3 = ok ? Wh[cs*9+3] : 0.f;
        float w4 = ok ? Wh[cs*9+4] : 0.f, w5 = ok ? Wh[cs*9+5] : 0.f;
        float w6 = ok ? Wh[cs*9+6] : 0.f, w7 = ok ? Wh[cs*9+7] : 0.f;
        float w8 = ok ? Wh[cs*9+8] : 0.f, bb = ok ? bh[cs]     : 0.f;
        uint4 q;
        if (half) {
            q.x = (bfu(bb) << 16) | bfu(w8);
            q.y = 0; q.z = 0; q.w = 0;
        } else {
            q.x = (bfu(w1) << 16) | bfu(w0);
            q.y = (bfu(w3) << 16) | bfu(w2);
            q.z = (bfu(w5) << 16) | bfu(w4);
            q.w = (bfu(w7) << 16) | bfu(w6);
        }
        wsA[g * 64 + lane] = q;
    }
}

__global__ __launch_bounds__(256, 4) void conv_p_mfma(
    const float* __restrict__ image, const float* __restrict__ Wp,
    const uint4* __restrict__ wsA, float* __restrict__ pout)
{
    const int tid  = threadIdx.x;
    const int wv   = tid >> 6;
    const int lane = tid & 63;
    const int half = lane >> 5;
    const int col0 = lane & 31;
    const int b    = blockIdx.z;
    const int y    = blockIdx.y * 4 + wv;     // wave's row
    const int x0   = blockIdx.x * 32;         // wave's strip
    const float* occ = image + (size_t)b * 131072;

    // global loads first (A-frags, rows, Wp) so latency overlaps the barrier
    uint4 q0 = wsA[0 * 64 + lane];
    uint4 q1 = wsA[1 * 64 + lane];
    uint4 q2 = wsA[2 * 64 + lane];
    uint4 q3 = wsA[3 * 64 + lane];
    uint4 q4 = wsA[4 * 64 + lane];

    int cc = x0 - 1 + lane;                   // lanes 0..33 hold the strip+halo
    bool cok = (lane < 34) & (cc >= 0) & (cc < 256);
    float r0 = (cok & (y >= 1))   ? occ[(y - 1) * 256 + cc] : 0.f;
    float r1 = cok                ? occ[y * 256 + cc]       : 0.f;
    float r2 = (cok & (y <= 254)) ? occ[(y + 1) * 256 + cc] : 0.f;

    __shared__ __align__(16) float lds_wp[160];
    if (tid < 160) lds_wp[tid] = (tid < 150) ? Wp[tid] : 0.f;
    __syncthreads();

    // 3x3 taps for pixel px = x0+col0 (loaded lanes col0..col0+2)
    float t0 = __shfl(r0, col0), t1 = __shfl(r0, col0 + 1), t2 = __shfl(r0, col0 + 2);
    float t3 = __shfl(r1, col0), t4 = __shfl(r1, col0 + 1), t5 = __shfl(r1, col0 + 2);
    float t6 = __shfl(r2, col0), t7 = __shfl(r2, col0 + 1), t8 = __shfl(r2, col0 + 2);

    // B fragment: half=0 -> k=0..7 = t0..t7; half=1 -> k=8 = t8, k=9 = 1.0
    union { uint32_t u[4]; short8 s; } bb;
    bb.u[0] = half ? pkbf(t8, 1.0f) : pkbf(t0, t1);
    bb.u[1] = half ? 0u : pkbf(t2, t3);
    bb.u[2] = half ? 0u : pkbf(t4, t5);
    bb.u[3] = half ? 0u : pkbf(t6, t7);
    short8 bfr = bb.s;

    union { uint4 q; short8 s; } ua0, ua1, ua2, ua3, ua4;
    ua0.q = q0; ua1.q = q1; ua2.q = q2; ua3.q = q3; ua4.q = q4;

    const f32x16 kZero = {};
    f32x16 d0 = __builtin_amdgcn_mfma_f32_32x32x16_bf16(ua0.s, bfr, kZero, 0, 0, 0);
    f32x16 d1 = __builtin_amdgcn_mfma_f32_32x32x16_bf16(ua1.s, bfr, kZero, 0, 0, 0);
    f32x16 d2 = __builtin_amdgcn_mfma_f32_32x32x16_bf16(ua2.s, bfr, kZero, 0, 0, 0);
    f32x16 d3 = __builtin_amdgcn_mfma_f32_32x32x16_bf16(ua3.s, bfr, kZero, 0, 0, 0);
    f32x16 d4 = __builtin_amdgcn_mfma_f32_32x32x16_bf16(ua4.s, bfr, kZero, 0, 0, 0);

    // s = sum_ch Wp[ch]*relu(h[ch]); C-row = (reg&3) + 8*(reg>>2) + 4*half
    float s0 = 0.f, s1 = 0.f, s2 = 0.f, s3 = 0.f;
#define RED(D, G)                                                            \
    {                                                                        \
        const float4 wA = *(const float4*)&lds_wp[32 * (G) + 0  + 4 * half]; \
        const float4 wB = *(const float4*)&lds_wp[32 * (G) + 8  + 4 * half]; \
        const float4 wC = *(const float4*)&lds_wp[32 * (G) + 16 + 4 * half]; \
        const float4 wD = *(const float4*)&lds_wp[32 * (G) + 24 + 4 * half]; \
        s0 = fmaf(wA.x, fmaxf(D[0],  0.f), s0);                              \
        s1 = fmaf(wA.y, fmaxf(D[1],  0.f), s1);                              \
        s2 = fmaf(wA.z, fmaxf(D[2],  0.f), s2);                              \
        s3 = fmaf(wA.w, fmaxf(D[3],  0.f), s3);                              \
        s0 = fmaf(wB.x, fmaxf(D[4],  0.f), s0);                              \
        s1 = fmaf(wB.y, fmaxf(D[5],  0.f), s1);                              \
        s2 = fmaf(wB.z, fmaxf(D[6],  0.f), s2);                              \
        s3 = fmaf(wB.w, fmaxf(D[7],  0.f), s3);                              \
        s0 = fmaf(wC.x, fmaxf(D[8],  0.f), s0);                              \
        s1 = fmaf(wC.y, fmaxf(D[9],  0.f), s1);                              \
        s2 = fmaf(wC.z, fmaxf(D[10], 0.f), s2);                              \
        s3 = fmaf(wC.w, fmaxf(D[11], 0.f), s3);                              \
        s0 = fmaf(wD.x, fmaxf(D[12], 0.f), s0);                              \
        s1 = fmaf(wD.y, fmaxf(D[13], 0.f), s1);                              \
        s2 = fmaf(wD.z, fmaxf(D[14], 0.f), s2);                              \
        s3 = fmaf(wD.w, fmaxf(D[15], 0.f), s3);                              \
    }
    RED(d0, 0) RED(d1, 1) RED(d2, 2) RED(d3, 3) RED(d4, 4)
#undef RED

    float s = (s0 + s1) + (s2 + s3);
    s += __shfl_xor(s, 32);   // combine the two half-wave channel sets

    float p = 1.f / (1.f + __expf(-s));
    if (lane < 32)
        pout[(size_t)b * 65536 + y * 256 + x0 + lane] = p;
}

__global__ __launch_bounds__(512, 2) void mvprop_kernel(
    const float* __restrict__ image, const float* __restrict__ pbuf,
    float* __restrict__ out)
{
    const int tid  = threadIdx.x;
    const int w    = tid >> 6;          // wave 0..7, owns ext rows 7w..7w+6
    const int lane = tid & 63;          // lane owns cols 4*lane..4*lane+3
    const int b    = blockIdx.z;
    const int gy0  = blockIdx.y * 16 - 20;   // ext row 0 -> global row gy0
    const int x4   = lane * 4;

    const float* rimg = image + (size_t)b * 131072 + 65536;  // channel 1
    const float* pp   = pbuf  + (size_t)b * 65536;

    float v[7][4], r[7][4], p[7][4];
#pragma unroll
    for (int i = 0; i < 7; ++i) {
        int gy = gy0 + w * 7 + i;
        if (gy >= 0 && gy < 256) {
            float4 rv = *(const float4*)&rimg[gy * 256 + x4];
            float4 pv = *(const float4*)&pp[gy * 256 + x4];
            r[i][0] = rv.x; r[i][1] = rv.y; r[i][2] = rv.z; r[i][3] = rv.w;
            p[i][0] = pv.x; p[i][1] = pv.y; p[i][2] = pv.z; p[i][3] = pv.w;
        } else {
            r[i][0] = r[i][1] = r[i][2] = r[i][3] = SENT;
            p[i][0] = p[i][1] = p[i][2] = p[i][3] = 0.f;
        }
        v[i][0] = r[i][0]; v[i][1] = r[i][1];
        v[i][2] = r[i][2]; v[i][3] = r[i][3];
    }

    __shared__ float4 gT[2][8][64];
    __shared__ float4 gB[2][8][64];

    for (int t = 0; t < 20; ++t) {
        int bf = t & 1;
        gT[bf][w][lane] = make_float4(v[0][0], v[0][1], v[0][2], v[0][3]);
        gB[bf][w][lane] = make_float4(v[6][0], v[6][1], v[6][2], v[6][3]);
        __syncthreads();
        float4 abv = (w > 0) ? gB[bf][w - 1][lane]
                             : make_float4(SENT, SENT, SENT, SENT);
        float4 blw = (w < 7) ? gT[bf][w + 1][lane]
                             : make_float4(SENT, SENT, SENT, SENT);

        float pv0 = abv.x, pv1 = abv.y, pv2 = abv.z, pv3 = abv.w;
#pragma unroll
        for (int i = 0; i < 7; ++i) {
            float c0 = v[i][0], c1 = v[i][1], c2 = v[i][2], c3 = v[i][3];
            float n0, n1, n2, n3;
            if (i < 6) { n0 = v[i+1][0]; n1 = v[i+1][1]; n2 = v[i+1][2]; n3 = v[i+1][3]; }
            else       { n0 = blw.x;     n1 = blw.y;     n2 = blw.z;     n3 = blw.w;     }
            float vm0 = fmaxf(pv0, fmaxf(c0, n0));
            float vm1 = fmaxf(pv1, fmaxf(c1, n1));
            float vm2 = fmaxf(pv2, fmaxf(c2, n2));
            float vm3 = fmaxf(pv3, fmaxf(c3, n3));
            float lL = __shfl_up(vm3, 1);
            lL = (lane == 0) ? SENT : lL;
            float rR = __shfl_down(vm0, 1);
            rR = (lane == 63) ? SENT : rR;
            float h0 = fmaxf(lL,  fmaxf(vm0, vm1));
            float h1 = fmaxf(vm0, fmaxf(vm1, vm2));
            float h2 = fmaxf(vm1, fmaxf(vm2, vm3));
            float h3 = fmaxf(vm2, fmaxf(vm3, rR));
            v[i][0] = fmaxf(c0, fmaf(p[i][0], h0 - r[i][0], r[i][0]));
            v[i][1] = fmaxf(c1, fmaf(p[i][1], h1 - r[i][1], r[i][1]));
            v[i][2] = fmaxf(c2, fmaf(p[i][2], h2 - r[i][2], r[i][2]));
            v[i][3] = fmaxf(c3, fmaf(p[i][3], h3 - r[i][3], r[i][3]));
            pv0 = c0; pv1 = c1; pv2 = c2; pv3 = c3;
        }
    }

    const float* occ = image + (size_t)b * 131072;
#pragma unroll
    for (int i = 0; i < 7; ++i) {
        int e = w * 7 + i;
        if (e >= 20 && e < 36) {
            int gy = gy0 + e;
            float4 ov = *(const float4*)&occ[gy * 256 + x4];
            float4 o;
            o.x = (ov.x > 0.49f) ? v[i][0] : -1.f;
            o.y = (ov.y > 0.49f) ? v[i][1] : -1.f;
            o.z = (ov.z > 0.49f) ? v[i][2] : -1.f;
            o.w = (ov.w > 0.49f) ? v[i][3] : -1.f;
            *(float4*)&out[(size_t)b * 65536 + gy * 256 + x4] = o;
        }
    }
}

extern "C" void kernel_launch(void* const* d_in, const int* in_sizes, int n_in,
                              void* d_out, int out_size, void* d_ws, size_t ws_size,
                              hipStream_t stream) {
    const float* image = (const float*)d_in[0];  // (16,2,256,256)
    const float* Wh    = (const float*)d_in[1];  // (150,1,3,3)
    const float* bh    = (const float*)d_in[2];  // (150,)
    const float* Wp    = (const float*)d_in[3];  // (1,150,1,1)
    float* out  = (float*)d_out;                 // (16,1,256,256) f32
    float* pbuf = (float*)d_ws;                  // 4 MB scratch for p
    uint4* wsA  = (uint4*)((char*)d_ws + (4 << 20));  // 5120 B A-fragments

    pack_a_kernel<<<1, 64, 0, stream>>>(Wh, bh, wsA);
    conv_p_mfma<<<dim3(8, 64, 16), dim3(256), 0, stream>>>(image, Wp, wsA, pbuf);
    mvprop_kernel<<<dim3(1, 16, 16), dim3(512), 0, stream>>>(image, pbuf, out);
}